// Round 4
// baseline (489.089 us; speedup 1.0000x reference)
//
#include <hip/hip_runtime.h>
#include <math.h>

#define BATCH 16384
#define N_CTX 10
#define N_NEG 20
#define DIM 300
#define N_ROWS 31                 // 10 ctx + 1 center + 20 neg
#define F4_PER_ROW 75             // 300 floats
#define TOT_F4 (N_ROWS * F4_PER_ROW)   // 2325
#define LOADS_PER_THR 10          // ceil(2325/256)

__device__ __forceinline__ float wave_reduce_sum(float v) {
#pragma unroll
    for (int m = 32; m >= 1; m >>= 1)
        v += __shfl_xor(v, m, 64);
    return v;
}

// log(sigmoid(x)): degree-4 series around 0 (|err|<1e-5 for |x|<0.5),
// exact stable form as fallback. Scores here are O(1e-3) by construction.
__device__ __forceinline__ float log_sigmoid_f(float x) {
    float ax = fabsf(x);
    if (ax < 0.5f) {
        float x2 = x * x;
        return -0.6931471805599453f + 0.5f * x + x2 * (-0.125f + x2 * (1.0f / 192.0f));
    }
    return fminf(x, 0.0f) - log1pf(__expf(-ax));
}

// One block per batch element. Load all 31 rows into LDS with ~10 independent
// float4 gathers per thread (explicit staging array => all loads in flight
// before any waitcnt), then compute mean + 21 dots from LDS.
__global__ __launch_bounds__(256) void cbow_loss_kernel(
    const int* __restrict__ context,     // [B, N_CTX]
    const int* __restrict__ center,      // [B]
    const int* __restrict__ negatives,   // [B, N_NEG]
    const float* __restrict__ ctx_w,     // [V, DIM]
    const float* __restrict__ cen_w,     // [V, DIM]
    float* __restrict__ partials)        // [BATCH]
{
    __shared__ float4 rows4[TOT_F4];     // 37200 B: rows[31][300] flattened
    __shared__ float  s_mean[DIM];       // 1200 B
    __shared__ int    s_idx[N_ROWS];
    __shared__ float  s_part[4];

    const int t    = threadIdx.x;
    const int lane = t & 63;
    const int wave = t >> 6;
    const int b    = blockIdx.x;
    const float* rows_f = (const float*)rows4;

    // ---- stage the 31 row indices ----
    if (t < N_CTX)            s_idx[t] = context[b * N_CTX + t];
    else if (t == N_CTX)      s_idx[t] = center[b];
    else if (t < N_ROWS)      s_idx[t] = negatives[b * N_NEG + (t - N_CTX - 1)];
    __syncthreads();

    // ---- gather phase: ~10 independent float4 loads per thread ----
    float4 v[LOADS_PER_THR];
#pragma unroll
    for (int k = 0; k < LOADS_PER_THR; ++k) {
        int j = t + 256 * k;
        if (j < TOT_F4) {
            int r = j / F4_PER_ROW;          // magic-mul const division
            int s = j - r * F4_PER_ROW;
            const float* base = (r < N_CTX) ? ctx_w : cen_w;
            const float* rowp = base + (size_t)s_idx[r] * DIM;
            v[k] = *(const float4*)(rowp + s * 4);
        }
    }
#pragma unroll
    for (int k = 0; k < LOADS_PER_THR; ++k) {
        int j = t + 256 * k;
        if (j < TOT_F4) rows4[j] = v[k];
    }
    __syncthreads();

    // ---- context mean: thread d handles dims d, d+256 ----
    for (int d = t; d < DIM; d += 256) {
        float acc = 0.f;
#pragma unroll
        for (int j = 0; j < N_CTX; ++j)
            acc += rows_f[j * DIM + d];
        s_mean[d] = acc * 0.1f;
    }
    __syncthreads();

    // ---- 21 dots: wave w handles dots n = w, w+4, ... ----
    // dot 0 = positive (row 10 = center), dot n>=1 = negative n-1 (row 10+n)
    float lsum = 0.f;
    for (int n = wave; n < N_NEG + 1; n += 4) {
        const float* rp = rows_f + (N_CTX + n) * DIM;
        float acc = 0.f;
        for (int d = lane; d < DIM; d += 64)
            acc += s_mean[d] * rp[d];
        float score = wave_reduce_sum(acc);
        lsum += (n == 0) ? log_sigmoid_f(score) : log_sigmoid_f(-score);
    }
    if (lane == 0) s_part[wave] = lsum;
    __syncthreads();
    if (t == 0)
        partials[b] = -(s_part[0] + s_part[1] + s_part[2] + s_part[3]);
}

__global__ __launch_bounds__(256) void reduce_partials_kernel(
    const float* __restrict__ partials, float* __restrict__ out)
{
    __shared__ double smem[256];
    double acc = 0.0;
    for (int i = threadIdx.x; i < BATCH; i += 256) acc += (double)partials[i];
    smem[threadIdx.x] = acc;
    __syncthreads();
    for (int s = 128; s > 0; s >>= 1) {
        if ((int)threadIdx.x < s) smem[threadIdx.x] += smem[threadIdx.x + s];
        __syncthreads();
    }
    if (threadIdx.x == 0) out[0] = (float)(smem[0] * (1.0 / (double)BATCH));
}

extern "C" void kernel_launch(void* const* d_in, const int* in_sizes, int n_in,
                              void* d_out, int out_size, void* d_ws, size_t ws_size,
                              hipStream_t stream) {
    const int*   context   = (const int*)d_in[0];
    const int*   center    = (const int*)d_in[1];
    const int*   negatives = (const int*)d_in[2];
    const float* ctx_w     = (const float*)d_in[3];
    const float* cen_w     = (const float*)d_in[4];
    float*       out       = (float*)d_out;
    float*       partials  = (float*)d_ws;   // 16384 floats = 64 KB

    cbow_loss_kernel<<<BATCH, 256, 0, stream>>>(
        context, center, negatives, ctx_w, cen_w, partials);
    reduce_partials_kernel<<<1, 256, 0, stream>>>(partials, out);
}

// Round 5
// 353.499 us; speedup vs baseline: 1.3836x; 1.3836x over previous
//
#include <hip/hip_runtime.h>
#include <math.h>

#define BATCH 16384
#define N_CTX 10
#define N_NEG 20
#define DIM 300
#define N_ROWS 31                 // 10 ctx + 1 center + 20 neg
#define F4_PER_ROW 75             // 300 floats
#define TOT_F4 (N_ROWS * F4_PER_ROW)   // 2325
#define LOADS_PER_THR 10          // ceil(2325/256)

__device__ __forceinline__ float wave_reduce_sum(float v) {
#pragma unroll
    for (int m = 32; m >= 1; m >>= 1)
        v += __shfl_xor(v, m, 64);
    return v;
}

// log(sigmoid(x)): degree-4 series around 0 (|err|<1e-5 for |x|<0.5),
// exact stable form as fallback. Scores here are O(1e-3) by construction.
__device__ __forceinline__ float log_sigmoid_f(float x) {
    float ax = fabsf(x);
    if (ax < 0.5f) {
        float x2 = x * x;
        return -0.6931471805599453f + 0.5f * x + x2 * (-0.125f + x2 * (1.0f / 192.0f));
    }
    return fminf(x, 0.0f) - log1pf(__expf(-ax));
}

// One block per batch element; all 31 rows staged to LDS via 10 independent
// float4 gathers per thread.
// __launch_bounds__(256,4): LDS (38.6 KB) already caps us at 4 blocks/CU =
// 4 waves/EU, so tell the allocator that => VGPR cap 128, staging array stays
// in registers. (Rounds 3/4 showed tighter caps scratch-spill the staging:
// WRITE_SIZE 461/596 MB.)
__global__ __launch_bounds__(256, 4) void cbow_loss_kernel(
    const int* __restrict__ context,     // [B, N_CTX]
    const int* __restrict__ center,      // [B]
    const int* __restrict__ negatives,   // [B, N_NEG]
    const float* __restrict__ ctx_w,     // [V, DIM]
    const float* __restrict__ cen_w,     // [V, DIM]
    float* __restrict__ partials)        // [BATCH]
{
    __shared__ float4 rows4[TOT_F4];     // 37200 B: rows[31][300] flattened
    __shared__ float  s_mean[DIM];       // 1200 B
    __shared__ int    s_idx[N_ROWS];
    __shared__ float  s_part[4];

    const int t    = threadIdx.x;
    const int lane = t & 63;
    const int wave = t >> 6;
    const int b    = blockIdx.x;
    const float* rows_f = (const float*)rows4;

    // ---- stage the 31 row indices ----
    if (t < N_CTX)            s_idx[t] = context[b * N_CTX + t];
    else if (t == N_CTX)      s_idx[t] = center[b];
    else if (t < N_ROWS)      s_idx[t] = negatives[b * N_NEG + (t - N_CTX - 1)];
    __syncthreads();

    // ---- gather: addresses first, then 10 independent loads, then stores.
    // Clamped (not exec-masked) addresses: OOB threads redundantly re-load
    // the last float4 — no conditional live ranges, no spill pressure.
    const float4* gp[LOADS_PER_THR];
#pragma unroll
    for (int k = 0; k < LOADS_PER_THR; ++k) {
        int j  = t + 256 * k;
        int jc = (j < TOT_F4) ? j : (TOT_F4 - 1);
        int r  = jc / F4_PER_ROW;            // magic-mul const division
        int s  = jc - r * F4_PER_ROW;
        const float* base = (r < N_CTX) ? ctx_w : cen_w;
        gp[k] = (const float4*)(base + (size_t)s_idx[r] * DIM + s * 4);
    }
    float4 v[LOADS_PER_THR];
#pragma unroll
    for (int k = 0; k < LOADS_PER_THR; ++k)
        v[k] = *gp[k];
#pragma unroll
    for (int k = 0; k < LOADS_PER_THR; ++k) {
        int j = t + 256 * k;
        if (j < TOT_F4) rows4[j] = v[k];     // only k=9 is partial (t<21)
    }
    __syncthreads();

    // ---- context mean ----
    for (int d = t; d < DIM; d += 256) {
        float acc = 0.f;
#pragma unroll
        for (int j = 0; j < N_CTX; ++j)
            acc += rows_f[j * DIM + d];
        s_mean[d] = acc * 0.1f;
    }
    __syncthreads();

    // ---- 21 dots: wave w handles dots n = w, w+4, ... ----
    float lsum = 0.f;
    for (int n = wave; n < N_NEG + 1; n += 4) {
        const float* rp = rows_f + (N_CTX + n) * DIM;
        float acc = 0.f;
        for (int d = lane; d < DIM; d += 64)
            acc += s_mean[d] * rp[d];
        float score = wave_reduce_sum(acc);
        lsum += (n == 0) ? log_sigmoid_f(score) : log_sigmoid_f(-score);
    }
    if (lane == 0) s_part[wave] = lsum;
    __syncthreads();
    if (t == 0)
        partials[b] = -(s_part[0] + s_part[1] + s_part[2] + s_part[3]);
}

__global__ __launch_bounds__(256) void reduce_partials_kernel(
    const float* __restrict__ partials, float* __restrict__ out)
{
    __shared__ double smem[256];
    double acc = 0.0;
    for (int i = threadIdx.x; i < BATCH; i += 256) acc += (double)partials[i];
    smem[threadIdx.x] = acc;
    __syncthreads();
    for (int s = 128; s > 0; s >>= 1) {
        if ((int)threadIdx.x < s) smem[threadIdx.x] += smem[threadIdx.x + s];
        __syncthreads();
    }
    if (threadIdx.x == 0) out[0] = (float)(smem[0] * (1.0 / (double)BATCH));
}

extern "C" void kernel_launch(void* const* d_in, const int* in_sizes, int n_in,
                              void* d_out, int out_size, void* d_ws, size_t ws_size,
                              hipStream_t stream) {
    const int*   context   = (const int*)d_in[0];
    const int*   center    = (const int*)d_in[1];
    const int*   negatives = (const int*)d_in[2];
    const float* ctx_w     = (const float*)d_in[3];
    const float* cen_w     = (const float*)d_in[4];
    float*       out       = (float*)d_out;
    float*       partials  = (float*)d_ws;   // 16384 floats = 64 KB

    cbow_loss_kernel<<<BATCH, 256, 0, stream>>>(
        context, center, negatives, ctx_w, cen_w, partials);
    reduce_partials_kernel<<<1, 256, 0, stream>>>(partials, out);
}